// Round 1
// baseline (7306.174 us; speedup 1.0000x reference)
//
#include <hip/hip_runtime.h>
#include <math.h>

// ---- model dims ----
#define BATCH   128
#define LSEQ    49
#define DM      512
#define NLAYERS 8
#define DSTATE  16
#define DCONV   4
#define DINNER  1024
#define DTRANK  32
#define EPSV    1e-5f

#define ROWS (BATCH*LSEQ)   // 6272

// ---- generic fp32 tiled GEMM: C = act(A@B + bias) [+ C if accum] ----
// A: M x K (lda), B: K x N (ldb), C: M x N (ldc)
#define BM 64
#define BN 64
#define BKK 16

__global__ __launch_bounds__(256) void gemm_f32(
    const float* __restrict__ A, int lda,
    const float* __restrict__ B, int ldb,
    float* __restrict__ C, int ldc,
    int M, int N, int K,
    const float* __restrict__ bias, int act, int accum)
{
    __shared__ float As[BKK][BM + 1];
    __shared__ float Bs[BKK][BN + 1];
    const int tid = threadIdx.x;
    const int bm = blockIdx.y * BM;
    const int bn = blockIdx.x * BN;
    const int tr = tid >> 4;   // 0..15
    const int tc = tid & 15;   // 0..15
    float acc[4][4] = {};

    for (int k0 = 0; k0 < K; k0 += BKK) {
        // load A tile (BM x BKK): e = tid + i*256 -> m = e/16, k = e%16
        #pragma unroll
        for (int i = 0; i < 4; ++i) {
            int e = tid + i * 256;
            int m = e >> 4, k = e & 15;
            int gm = bm + m, gk = k0 + k;
            float v = 0.f;
            if (gm < M && gk < K) v = A[(long)gm * lda + gk];
            As[k][m] = v;
        }
        // load B tile (BKK x BN): e -> k = e/64, n = e%64
        #pragma unroll
        for (int i = 0; i < 4; ++i) {
            int e = tid + i * 256;
            int k = e >> 6, n = e & 63;
            int gk = k0 + k, gn = bn + n;
            float v = 0.f;
            if (gk < K && gn < N) v = B[(long)gk * ldb + gn];
            Bs[k][n] = v;
        }
        __syncthreads();
        #pragma unroll
        for (int kk = 0; kk < BKK; ++kk) {
            float a[4], b[4];
            #pragma unroll
            for (int i = 0; i < 4; ++i) a[i] = As[kk][tr * 4 + i];
            #pragma unroll
            for (int j = 0; j < 4; ++j) b[j] = Bs[kk][tc * 4 + j];
            #pragma unroll
            for (int i = 0; i < 4; ++i)
                #pragma unroll
                for (int j = 0; j < 4; ++j)
                    acc[i][j] = fmaf(a[i], b[j], acc[i][j]);
        }
        __syncthreads();
    }

    #pragma unroll
    for (int i = 0; i < 4; ++i) {
        int row = bm + tr * 4 + i;
        if (row >= M) continue;
        #pragma unroll
        for (int j = 0; j < 4; ++j) {
            int col = bn + tc * 4 + j;
            if (col >= N) continue;
            float c = acc[i][j];
            if (bias) c += bias[col];
            if (act == 1) {                 // softplus
                c = (c > 20.f) ? c : log1pf(expf(c));
            } else if (act == 2) {          // exact gelu
                c = 0.5f * c * (1.f + erff(c * 0.7071067811865476f));
            }
            long idx = (long)row * ldc + col;
            if (accum) c += C[idx];
            C[idx] = c;
        }
    }
}

// ---- patch embed + pos embed: h[b,l,d] ----
__global__ __launch_bounds__(256) void patch_k(
    const float* __restrict__ x, const float* __restrict__ pw,
    const float* __restrict__ pb, const float* __restrict__ pos,
    float* __restrict__ h)
{
    int idx = blockIdx.x * 256 + threadIdx.x;     // BATCH*LSEQ*DM
    int d = idx & (DM - 1);
    int l = (idx >> 9) % LSEQ;
    int b = idx / (DM * LSEQ);
    int gi = l / 7, gj = l % 7;
    float acc = pb[d];
    #pragma unroll
    for (int k = 0; k < 16; ++k) {
        int pi = k >> 2, pj = k & 3;
        acc = fmaf(x[((long)b * 28 + gi * 4 + pi) * 28 + gj * 4 + pj],
                   pw[d * 16 + k], acc);
    }
    h[idx] = acc + pos[l * DM + d];
}

// ---- layernorm over last dim (512), one wave per row ----
__global__ __launch_bounds__(256) void layernorm_k(
    const float* __restrict__ x, const float* __restrict__ g,
    const float* __restrict__ bb, float* __restrict__ y, int rows)
{
    int wave = threadIdx.x >> 6;
    int lane = threadIdx.x & 63;
    int row = blockIdx.x * 4 + wave;
    if (row >= rows) return;
    const float* xr = x + (long)row * DM;
    float v[8];
    float s = 0.f, q = 0.f;
    #pragma unroll
    for (int i = 0; i < 8; ++i) {
        v[i] = xr[lane * 8 + i];
        s += v[i]; q += v[i] * v[i];
    }
    #pragma unroll
    for (int o = 32; o > 0; o >>= 1) {
        s += __shfl_down(s, o, 64);
        q += __shfl_down(q, o, 64);
    }
    s = __shfl(s, 0, 64); q = __shfl(q, 0, 64);
    float m = s * (1.f / DM);
    float var = q * (1.f / DM) - m * m;
    float rs = rsqrtf(var + EPSV);
    float* yr = y + (long)row * DM;
    #pragma unroll
    for (int i = 0; i < 8; ++i) {
        int c = lane * 8 + i;
        yr[c] = (v[i] - m) * rs * g[c] + bb[c];
    }
}

// ---- causal depthwise conv (k=4) + silu; reads xp half of xz ----
__global__ __launch_bounds__(256) void conv_silu_k(
    const float* __restrict__ xz, const float* __restrict__ cw,
    const float* __restrict__ cb, float* __restrict__ xp)
{
    int idx = blockIdx.x * 256 + threadIdx.x;     // BATCH*LSEQ*DINNER
    int d = idx & (DINNER - 1);
    int l = (idx >> 10) % LSEQ;
    int b = idx / (DINNER * LSEQ);
    float acc = cb[d];
    #pragma unroll
    for (int k = 0; k < DCONV; ++k) {
        int ls = l - 3 + k;
        if (ls >= 0)
            acc = fmaf(xz[(long)(b * LSEQ + ls) * (2 * DINNER) + d],
                       cw[d * DCONV + k], acc);
    }
    acc = acc / (1.f + expf(-acc));   // silu
    xp[idx] = acc;
}

// ---- selective scan: one thread per (b,d); sequential over L ----
// dbc row layout: [0:32) dt_lo, [32:48) Bm, [48:64) Cm
__global__ __launch_bounds__(256) void scan_k(
    const float* __restrict__ xp,   // (ROWS, DINNER)
    const float* __restrict__ dt,   // (ROWS, DINNER)
    const float* __restrict__ dbc,  // (ROWS, 64)
    const float* __restrict__ xz,   // (ROWS, 2048), z at col 1024+
    const float* __restrict__ A_log,  // layer base (DINNER*DSTATE)
    const float* __restrict__ Dp,     // layer base (DINNER)
    float* __restrict__ y)            // (ROWS, DINNER)
{
    __shared__ float smB[LSEQ * DSTATE];
    __shared__ float smC[LSEQ * DSTATE];
    int b = blockIdx.x >> 2;
    int d = ((blockIdx.x & 3) << 8) + threadIdx.x;
    for (int e = threadIdx.x; e < LSEQ * DSTATE; e += 256) {
        int l = e >> 4, n = e & 15;
        const float* row = dbc + (long)(b * LSEQ + l) * 64;
        smB[e] = row[32 + n];
        smC[e] = row[48 + n];
    }
    __syncthreads();
    float Arow[DSTATE];
    #pragma unroll
    for (int n = 0; n < DSTATE; ++n)
        Arow[n] = -expf(A_log[d * DSTATE + n]);
    float Dv = Dp[d];
    float h[DSTATE] = {};
    for (int l = 0; l < LSEQ; ++l) {
        long r = (long)(b * LSEQ + l);
        float dtv = dt[r * DINNER + d];
        float xv  = xp[r * DINNER + d];
        float acc = 0.f;
        const float* Brow = smB + l * DSTATE;
        const float* Crow = smC + l * DSTATE;
        #pragma unroll
        for (int n = 0; n < DSTATE; ++n) {
            float dA = expf(dtv * Arow[n]);
            h[n] = dA * h[n] + dtv * Brow[n] * xv;
            acc = fmaf(h[n], Crow[n], acc);
        }
        acc = fmaf(Dv, xv, acc);
        float zv = xz[r * (2 * DINNER) + DINNER + d];
        acc *= zv / (1.f + expf(-zv));    // * silu(z)
        y[r * DINNER + d] = acc;
    }
}

// ---- mean over L + layernorm -> pooled (BATCH, DM) ----
__global__ __launch_bounds__(256) void pool_ln_k(
    const float* __restrict__ h, const float* __restrict__ g,
    const float* __restrict__ bb, float* __restrict__ pooled)
{
    __shared__ float red[8];
    int b = blockIdx.x;
    int tid = threadIdx.x;
    int c0 = tid, c1 = tid + 256;
    float v0 = 0.f, v1 = 0.f;
    for (int l = 0; l < LSEQ; ++l) {
        const float* row = h + (long)(b * LSEQ + l) * DM;
        v0 += row[c0]; v1 += row[c1];
    }
    v0 *= (1.f / LSEQ); v1 *= (1.f / LSEQ);
    float s = v0 + v1, q = v0 * v0 + v1 * v1;
    #pragma unroll
    for (int o = 32; o > 0; o >>= 1) {
        s += __shfl_down(s, o, 64);
        q += __shfl_down(q, o, 64);
    }
    int lane = tid & 63, wave = tid >> 6;
    if (lane == 0) { red[wave] = s; red[4 + wave] = q; }
    __syncthreads();
    if (tid == 0) {
        float S = red[0] + red[1] + red[2] + red[3];
        float Q = red[4] + red[5] + red[6] + red[7];
        float m = S * (1.f / DM);
        red[0] = m;
        red[1] = rsqrtf(Q * (1.f / DM) - m * m + EPSV);
    }
    __syncthreads();
    float m = red[0], rs = red[1];
    pooled[b * DM + c0] = (v0 - m) * rs * g[c0] + bb[c0];
    pooled[b * DM + c1] = (v1 - m) * rs * g[c1] + bb[c1];
}

extern "C" void kernel_launch(void* const* d_in, const int* in_sizes, int n_in,
                              void* d_out, int out_size, void* d_ws, size_t ws_size,
                              hipStream_t stream)
{
    const float* x       = (const float*)d_in[0];
    const float* patch_w = (const float*)d_in[1];
    const float* patch_b = (const float*)d_in[2];
    const float* pos     = (const float*)d_in[3];
    const float* Win     = (const float*)d_in[4];
    const float* conv_w  = (const float*)d_in[5];
    const float* conv_b  = (const float*)d_in[6];
    const float* Wx      = (const float*)d_in[7];
    const float* Wdt     = (const float*)d_in[8];
    const float* bdt     = (const float*)d_in[9];
    const float* A_log   = (const float*)d_in[10];
    const float* Dp      = (const float*)d_in[11];
    const float* Wout    = (const float*)d_in[12];
    const float* ln_g    = (const float*)d_in[13];
    const float* ln_b    = (const float*)d_in[14];
    const float* norm_g  = (const float*)d_in[15];
    const float* norm_b  = (const float*)d_in[16];
    const float* W1      = (const float*)d_in[17];
    const float* b1      = (const float*)d_in[18];
    const float* W2      = (const float*)d_in[19];
    const float* b2      = (const float*)d_in[20];
    float* out = (float*)d_out;

    // workspace layout (floats)
    float* ws = (float*)d_ws;
    float* h      = ws;                       // ROWS*DM      = 3,211,264
    float* hln    = h + (long)ROWS * DM;      // ROWS*DM
    float* xz     = hln + (long)ROWS * DM;    // ROWS*2048    = 12,845,056
    float* xp     = xz + (long)ROWS * 2 * DINNER;  // ROWS*DINNER
    float* dbc    = xp + (long)ROWS * DINNER;      // ROWS*64
    float* dtb    = dbc + (long)ROWS * 64;         // ROWS*DINNER
    float* yb     = dtb + (long)ROWS * DINNER;     // ROWS*DINNER
    float* pooled = yb + (long)ROWS * DINNER;      // BATCH*DM
    float* hid    = pooled + (long)BATCH * DM;     // BATCH*256

    // 1. patch + pos embed
    patch_k<<<(ROWS * DM) / 256, 256, 0, stream>>>(x, patch_w, patch_b, pos, h);

    for (int layer = 0; layer < NLAYERS; ++layer) {
        // 2. layernorm
        layernorm_k<<<(ROWS + 3) / 4, 256, 0, stream>>>(
            h, ln_g + layer * DM, ln_b + layer * DM, hln, ROWS);
        // 3. xz = hln @ Win
        gemm_f32<<<dim3(2 * DINNER / BN, ROWS / BM), 256, 0, stream>>>(
            hln, DM, Win + (long)layer * DM * 2 * DINNER, 2 * DINNER,
            xz, 2 * DINNER, ROWS, 2 * DINNER, DM, nullptr, 0, 0);
        // 4. conv + silu
        conv_silu_k<<<(ROWS * DINNER) / 256, 256, 0, stream>>>(
            xz, conv_w + (long)layer * DINNER * DCONV, conv_b + (long)layer * DINNER, xp);
        // 5. dbc = xp @ Wx
        gemm_f32<<<dim3(1, ROWS / BM), 256, 0, stream>>>(
            xp, DINNER, Wx + (long)layer * DINNER * 64, 64,
            dbc, 64, ROWS, 64, DINNER, nullptr, 0, 0);
        // 6. dt = softplus(dt_lo @ Wdt + bdt)
        gemm_f32<<<dim3(DINNER / BN, ROWS / BM), 256, 0, stream>>>(
            dbc, 64, Wdt + (long)layer * DTRANK * DINNER, DINNER,
            dtb, DINNER, ROWS, DINNER, DTRANK, bdt + (long)layer * DINNER, 1, 0);
        // 7. selective scan (+ D skip + silu(z) gate)
        scan_k<<<BATCH * (DINNER / 256), 256, 0, stream>>>(
            xp, dtb, dbc, xz,
            A_log + (long)layer * DINNER * DSTATE, Dp + (long)layer * DINNER, yb);
        // 8. h += y @ Wout
        gemm_f32<<<dim3(DM / BN, ROWS / BM), 256, 0, stream>>>(
            yb, DINNER, Wout + (long)layer * DINNER * DM, DM,
            h, DM, ROWS, DM, DINNER, nullptr, 0, 1);
    }

    // 9. pool + final layernorm
    pool_ln_k<<<BATCH, 256, 0, stream>>>(h, norm_g, norm_b, pooled);
    // 10. hid = gelu(pooled @ W1 + b1)
    gemm_f32<<<dim3(256 / BN, BATCH / BM), 256, 0, stream>>>(
        pooled, DM, W1, 256, hid, 256, BATCH, 256, DM, b1, 2, 0);
    // 11. out = hid @ W2 + b2
    gemm_f32<<<dim3(1, BATCH / BM), 256, 0, stream>>>(
        hid, 256, W2, 10, out, 10, BATCH, 10, 256, b2, 0, 0);
}

// Round 2
// 2216.882 us; speedup vs baseline: 3.2957x; 3.2957x over previous
//
#include <hip/hip_runtime.h>
#include <math.h>

// ---- model dims ----
#define BATCH   128
#define LSEQ    49
#define DM      512
#define NLAYERS 8
#define DSTATE  16
#define DCONV   4
#define DINNER  1024
#define DTRANK  32
#define EPSV    1e-5f
#define ROWS (BATCH*LSEQ)   // 6272

typedef unsigned short bf16_t;
typedef __attribute__((ext_vector_type(8))) short short8;   // 8 bf16 (4 VGPRs)
typedef __attribute__((ext_vector_type(4))) float f32x4;

__device__ __forceinline__ bf16_t f2b(float f) {
    union { float f; unsigned u; } v; v.f = f;
    return (bf16_t)((v.u + 0x7fffu + ((v.u >> 16) & 1u)) >> 16);   // RNE
}
__device__ __forceinline__ float b2f(bf16_t h) {
    union { unsigned u; float f; } v; v.u = ((unsigned)h) << 16;
    return v.f;
}
__device__ __forceinline__ void gload_lds16(const void* g, void* l) {
    __builtin_amdgcn_global_load_lds(
        (const __attribute__((address_space(1))) unsigned int*)g,
        (__attribute__((address_space(3))) unsigned int*)l, 16, 0, 0);
}

// =====================================================================
// bf16 MFMA GEMM, m97 structure: 128x128 tile, BK=32, global_load_lds x16B.
// A: M x K row-major bf16.  Bt: N x K row-major bf16 (i.e. B transposed).
// C (fp32) or Cb (bf16) output, optional bias + softplus, optional accum.
// Requires M%128==0, K%32==0; N-edge handled by guard (Bt padded to 128 rows).
// =====================================================================
__global__ __launch_bounds__(256) void gemm_bf16(
    const bf16_t* __restrict__ A, int lda,
    const bf16_t* __restrict__ Bt, int ldb,
    const float* __restrict__ bias,
    float* __restrict__ C, int ldc,
    int M, int N, int K, int act, int accum,
    bf16_t* __restrict__ Cb)
{
    __shared__ bf16_t As[128 * 32];   // row-major, 64B per row
    __shared__ bf16_t Bs[128 * 32];

    const int tid  = threadIdx.x;
    const int wave = tid >> 6;
    const int lane = tid & 63;
    const int bm = blockIdx.y * 128;
    const int bn = blockIdx.x * 128;
    const int wr = wave >> 1;          // wave row quadrant (0..1)
    const int wc = wave & 1;           // wave col quadrant (0..1)
    const int q  = lane >> 4;          // 0..3
    const int lm = lane & 15;

    // staging: chunk = 1024B = 16 rows x 64B; wave w stages chunks {2w,2w+1}
    const int rowInChunk = lane >> 2;        // 0..15
    const int col8 = (lane & 3) * 8;         // bf16 element offset in row

    f32x4 acc[4][4];
    #pragma unroll
    for (int i = 0; i < 4; ++i)
        #pragma unroll
        for (int j = 0; j < 4; ++j)
            acc[i][j] = (f32x4){0.f, 0.f, 0.f, 0.f};

    for (int k0 = 0; k0 < K; k0 += 32) {
        #pragma unroll
        for (int i = 0; i < 2; ++i) {
            int chunk = wave * 2 + i;
            int r = chunk * 16 + rowInChunk;
            const bf16_t* ga = A  + (size_t)(bm + r) * lda + k0 + col8;
            const bf16_t* gb = Bt + (size_t)(bn + r) * ldb + k0 + col8;
            gload_lds16(ga, &As[chunk * 512]);
            gload_lds16(gb, &Bs[chunk * 512]);
        }
        __syncthreads();

        short8 af[4], bq[4];
        #pragma unroll
        for (int t = 0; t < 4; ++t) {
            af[t] = *(const short8*)&As[(wr * 64 + t * 16 + lm) * 32 + q * 8];
            bq[t] = *(const short8*)&Bs[(wc * 64 + t * 16 + lm) * 32 + q * 8];
        }
        #pragma unroll
        for (int mt = 0; mt < 4; ++mt)
            #pragma unroll
            for (int nt = 0; nt < 4; ++nt)
                acc[mt][nt] = __builtin_amdgcn_mfma_f32_16x16x32_bf16(
                    af[mt], bq[nt], acc[mt][nt], 0, 0, 0);
        __syncthreads();
    }

    // epilogue: C/D layout col=lane&15, row=q*4+reg
    #pragma unroll
    for (int mt = 0; mt < 4; ++mt) {
        #pragma unroll
        for (int nt = 0; nt < 4; ++nt) {
            int col = bn + wc * 64 + nt * 16 + lm;
            if (col >= N) continue;
            float bv = bias ? bias[col] : 0.f;
            #pragma unroll
            for (int r = 0; r < 4; ++r) {
                int row = bm + wr * 64 + mt * 16 + q * 4 + r;
                float c = acc[mt][nt][r] + bv;
                if (act == 1) c = (c > 20.f) ? c : log1pf(expf(c));  // softplus
                size_t idx = (size_t)row * ldc + col;
                if (accum) c += C[idx];
                if (Cb) Cb[idx] = f2b(c);
                else    C[idx] = c;
            }
        }
    }
}

// ---- transpose + fp32->bf16 convert: out[z][n][k] = in[z][k][n], pad n>=Nd=0
__global__ __launch_bounds__(256) void transpose_bf16_k(
    const float* __restrict__ in, bf16_t* __restrict__ out,
    int Kd, int Nd, long in_stride, long out_stride)
{
    __shared__ float tile[32][33];
    int z = blockIdx.z;
    const float* src = in + (size_t)z * in_stride;
    bf16_t* dst = out + (size_t)z * out_stride;
    int n0 = blockIdx.x * 32, k0 = blockIdx.y * 32;
    int tx = threadIdx.x & 31, ty = threadIdx.x >> 5;  // ty 0..7
    #pragma unroll
    for (int i = 0; i < 4; ++i) {
        int n = n0 + tx;
        tile[ty + i * 8][tx] = (n < Nd) ? src[(size_t)(k0 + ty + i * 8) * Nd + n] : 0.f;
    }
    __syncthreads();
    #pragma unroll
    for (int i = 0; i < 4; ++i) {
        int n = n0 + ty + i * 8;
        dst[(size_t)n * Kd + k0 + tx] = f2b(tile[tx][ty + i * 8]);
    }
}

// ---- patch embed + pos embed ----
__global__ __launch_bounds__(256) void patch_k(
    const float* __restrict__ x, const float* __restrict__ pw,
    const float* __restrict__ pb, const float* __restrict__ pos,
    float* __restrict__ h)
{
    int idx = blockIdx.x * 256 + threadIdx.x;
    int d = idx & (DM - 1);
    int l = (idx >> 9) % LSEQ;
    int b = idx / (DM * LSEQ);
    int gi = l / 7, gj = l % 7;
    float acc = pb[d];
    #pragma unroll
    for (int k = 0; k < 16; ++k) {
        int pi = k >> 2, pj = k & 3;
        acc = fmaf(x[((long)b * 28 + gi * 4 + pi) * 28 + gj * 4 + pj],
                   pw[d * 16 + k], acc);
    }
    h[idx] = acc + pos[l * DM + d];
}

// ---- layernorm (512) -> bf16, one wave per row ----
__global__ __launch_bounds__(256) void layernorm_bf16_k(
    const float* __restrict__ x, const float* __restrict__ g,
    const float* __restrict__ bb, bf16_t* __restrict__ y, int rows)
{
    int wave = threadIdx.x >> 6;
    int lane = threadIdx.x & 63;
    int row = blockIdx.x * 4 + wave;
    if (row >= rows) return;
    const float* xr = x + (long)row * DM;
    float v[8];
    float s = 0.f, qq = 0.f;
    #pragma unroll
    for (int i = 0; i < 8; ++i) {
        v[i] = xr[lane * 8 + i];
        s += v[i]; qq += v[i] * v[i];
    }
    #pragma unroll
    for (int o = 32; o > 0; o >>= 1) {
        s += __shfl_down(s, o, 64);
        qq += __shfl_down(qq, o, 64);
    }
    s = __shfl(s, 0, 64); qq = __shfl(qq, 0, 64);
    float m = s * (1.f / DM);
    float var = qq * (1.f / DM) - m * m;
    float rs = rsqrtf(var + EPSV);
    bf16_t* yr = y + (long)row * DM;
    #pragma unroll
    for (int i = 0; i < 8; ++i) {
        int c = lane * 8 + i;
        yr[c] = f2b((v[i] - m) * rs * g[c] + bb[c]);
    }
}

// ---- causal depthwise conv (k=4) + silu; fp32 + bf16 outputs ----
__global__ __launch_bounds__(256) void conv_silu_k(
    const float* __restrict__ xz, const float* __restrict__ cw,
    const float* __restrict__ cb, float* __restrict__ xp,
    bf16_t* __restrict__ xpb)
{
    int idx = blockIdx.x * 256 + threadIdx.x;
    int d = idx & (DINNER - 1);
    int l = (idx >> 10) % LSEQ;
    int b = idx / (DINNER * LSEQ);
    float acc = cb[d];
    #pragma unroll
    for (int k = 0; k < DCONV; ++k) {
        int ls = l - 3 + k;
        if (ls >= 0)
            acc = fmaf(xz[(long)(b * LSEQ + ls) * (2 * DINNER) + d],
                       cw[d * DCONV + k], acc);
    }
    acc = acc / (1.f + __expf(-acc));
    xp[idx] = acc;
    xpb[idx] = f2b(acc);
}

// ---- extract dt_lo columns of dbc -> compact bf16 (ROWS x 32) ----
__global__ __launch_bounds__(256) void dtlo_k(
    const float* __restrict__ dbc, bf16_t* __restrict__ dtlo)
{
    int idx = blockIdx.x * 256 + threadIdx.x;
    int r = idx >> 5, j = idx & 31;
    dtlo[idx] = f2b(dbc[(size_t)r * 64 + j]);
}

// ---- selective scan: one thread per (b,d), y out in bf16 ----
__global__ __launch_bounds__(256) void scan_k(
    const float* __restrict__ xp,     // (ROWS, DINNER) fp32
    const bf16_t* __restrict__ dt,    // (ROWS, DINNER) bf16
    const float* __restrict__ dbc,    // (ROWS, 64) fp32
    const float* __restrict__ xz,     // (ROWS, 2048), z at 1024+
    const float* __restrict__ A_log,
    const float* __restrict__ Dp,
    bf16_t* __restrict__ y)           // (ROWS, DINNER) bf16
{
    __shared__ float smB[LSEQ * DSTATE];
    __shared__ float smC[LSEQ * DSTATE];
    int b = blockIdx.x >> 2;
    int d = ((blockIdx.x & 3) << 8) + threadIdx.x;
    for (int e = threadIdx.x; e < LSEQ * DSTATE; e += 256) {
        int l = e >> 4, n = e & 15;
        const float* row = dbc + (long)(b * LSEQ + l) * 64;
        smB[e] = row[32 + n];
        smC[e] = row[48 + n];
    }
    __syncthreads();
    float Arow[DSTATE];
    #pragma unroll
    for (int n = 0; n < DSTATE; ++n)
        Arow[n] = -__expf(A_log[d * DSTATE + n] * 1.44269504088896f) ;
    // NOTE: __expf computes expf via exp2; A_log values are ln(1..16) -> exact
    // relation: exp(x) = exp2(x*log2e). Using explicit conversion above.
    float Dv = Dp[d];
    float h[DSTATE] = {};
    for (int l = 0; l < LSEQ; ++l) {
        long r = (long)(b * LSEQ + l);
        float dtv = b2f(dt[r * DINNER + d]);
        float xv  = xp[r * DINNER + d];
        float acc = 0.f;
        const float* Brow = smB + l * DSTATE;
        const float* Crow = smC + l * DSTATE;
        #pragma unroll
        for (int n = 0; n < DSTATE; ++n) {
            float dA = __expf(dtv * Arow[n]);
            h[n] = dA * h[n] + dtv * Brow[n] * xv;
            acc = fmaf(h[n], Crow[n], acc);
        }
        acc = fmaf(Dv, xv, acc);
        float zv = xz[r * (2 * DINNER) + DINNER + d];
        acc *= zv / (1.f + __expf(-zv));
        y[r * DINNER + d] = f2b(acc);
    }
}

// ---- mean over L + layernorm -> pooled (BATCH, DM) ----
__global__ __launch_bounds__(256) void pool_ln_k(
    const float* __restrict__ h, const float* __restrict__ g,
    const float* __restrict__ bb, float* __restrict__ pooled)
{
    __shared__ float red[8];
    int b = blockIdx.x;
    int tid = threadIdx.x;
    int c0 = tid, c1 = tid + 256;
    float v0 = 0.f, v1 = 0.f;
    for (int l = 0; l < LSEQ; ++l) {
        const float* row = h + (long)(b * LSEQ + l) * DM;
        v0 += row[c0]; v1 += row[c1];
    }
    v0 *= (1.f / LSEQ); v1 *= (1.f / LSEQ);
    float s = v0 + v1, q = v0 * v0 + v1 * v1;
    #pragma unroll
    for (int o = 32; o > 0; o >>= 1) {
        s += __shfl_down(s, o, 64);
        q += __shfl_down(q, o, 64);
    }
    int lane = tid & 63, wave = tid >> 6;
    if (lane == 0) { red[wave] = s; red[4 + wave] = q; }
    __syncthreads();
    if (tid == 0) {
        float S = red[0] + red[1] + red[2] + red[3];
        float Q = red[4] + red[5] + red[6] + red[7];
        float m = S * (1.f / DM);
        red[0] = m;
        red[1] = rsqrtf(Q * (1.f / DM) - m * m + EPSV);
    }
    __syncthreads();
    float m = red[0], rs = red[1];
    pooled[b * DM + c0] = (v0 - m) * rs * g[c0] + bb[c0];
    pooled[b * DM + c1] = (v1 - m) * rs * g[c1] + bb[c1];
}

// ---- small fp32 GEMM for the head (M=128) ----
#define BM 64
#define BN 64
#define BKK 16
__global__ __launch_bounds__(256) void gemm_f32(
    const float* __restrict__ A, int lda,
    const float* __restrict__ B, int ldb,
    float* __restrict__ C, int ldc,
    int M, int N, int K,
    const float* __restrict__ bias, int act)
{
    __shared__ float As[BKK][BM + 1];
    __shared__ float Bs[BKK][BN + 1];
    const int tid = threadIdx.x;
    const int bm = blockIdx.y * BM;
    const int bn = blockIdx.x * BN;
    const int tr = tid >> 4;
    const int tc = tid & 15;
    float acc[4][4] = {};
    for (int k0 = 0; k0 < K; k0 += BKK) {
        #pragma unroll
        for (int i = 0; i < 4; ++i) {
            int e = tid + i * 256;
            int m = e >> 4, k = e & 15;
            int gm = bm + m, gk = k0 + k;
            As[k][m] = (gm < M && gk < K) ? A[(long)gm * lda + gk] : 0.f;
        }
        #pragma unroll
        for (int i = 0; i < 4; ++i) {
            int e = tid + i * 256;
            int k = e >> 6, n = e & 63;
            int gk = k0 + k, gn = bn + n;
            Bs[k][n] = (gk < K && gn < N) ? B[(long)gk * ldb + gn] : 0.f;
        }
        __syncthreads();
        #pragma unroll
        for (int kk = 0; kk < BKK; ++kk) {
            float a[4], b[4];
            #pragma unroll
            for (int i = 0; i < 4; ++i) a[i] = As[kk][tr * 4 + i];
            #pragma unroll
            for (int j = 0; j < 4; ++j) b[j] = Bs[kk][tc * 4 + j];
            #pragma unroll
            for (int i = 0; i < 4; ++i)
                #pragma unroll
                for (int j = 0; j < 4; ++j)
                    acc[i][j] = fmaf(a[i], b[j], acc[i][j]);
        }
        __syncthreads();
    }
    #pragma unroll
    for (int i = 0; i < 4; ++i) {
        int row = bm + tr * 4 + i;
        if (row >= M) continue;
        #pragma unroll
        for (int j = 0; j < 4; ++j) {
            int col = bn + tc * 4 + j;
            if (col >= N) continue;
            float c = acc[i][j];
            if (bias) c += bias[col];
            if (act == 2) c = 0.5f * c * (1.f + erff(c * 0.7071067811865476f));
            C[(long)row * ldc + col] = c;
        }
    }
}

extern "C" void kernel_launch(void* const* d_in, const int* in_sizes, int n_in,
                              void* d_out, int out_size, void* d_ws, size_t ws_size,
                              hipStream_t stream)
{
    const float* x       = (const float*)d_in[0];
    const float* patch_w = (const float*)d_in[1];
    const float* patch_b = (const float*)d_in[2];
    const float* pos     = (const float*)d_in[3];
    const float* Win     = (const float*)d_in[4];
    const float* conv_w  = (const float*)d_in[5];
    const float* conv_b  = (const float*)d_in[6];
    const float* Wx      = (const float*)d_in[7];
    const float* Wdt     = (const float*)d_in[8];
    const float* bdt     = (const float*)d_in[9];
    const float* A_log   = (const float*)d_in[10];
    const float* Dp      = (const float*)d_in[11];
    const float* Wout    = (const float*)d_in[12];
    const float* ln_g    = (const float*)d_in[13];
    const float* ln_b    = (const float*)d_in[14];
    const float* norm_g  = (const float*)d_in[15];
    const float* norm_b  = (const float*)d_in[16];
    const float* W1      = (const float*)d_in[17];
    const float* b1      = (const float*)d_in[18];
    const float* W2      = (const float*)d_in[19];
    const float* b2      = (const float*)d_in[20];
    float* out = (float*)d_out;

    // ---- workspace carve (aligned 256B) ----
    char* p = (char*)d_ws;
    auto alloc = [&](size_t bytes) {
        char* r = p; p += (bytes + 255) & ~(size_t)255; return r;
    };
    float*  h     = (float*) alloc((size_t)ROWS * DM * 4);
    float*  xz    = (float*) alloc((size_t)ROWS * 2 * DINNER * 4);
    float*  xp    = (float*) alloc((size_t)ROWS * DINNER * 4);
    float*  dbc   = (float*) alloc((size_t)ROWS * 64 * 4);
    bf16_t* hln   = (bf16_t*)alloc((size_t)ROWS * DM * 2);
    bf16_t* xpb   = (bf16_t*)alloc((size_t)ROWS * DINNER * 2);  // also y
    bf16_t* dtb   = (bf16_t*)alloc((size_t)ROWS * DINNER * 2);
    bf16_t* dtlo  = (bf16_t*)alloc((size_t)ROWS * 32 * 2);
    bf16_t* WinT  = (bf16_t*)alloc((size_t)NLAYERS * 2048 * 512 * 2);
    bf16_t* WxT   = (bf16_t*)alloc((size_t)NLAYERS * 128 * 1024 * 2);
    bf16_t* WdtT  = (bf16_t*)alloc((size_t)NLAYERS * 1024 * 32 * 2);
    bf16_t* WoutT = (bf16_t*)alloc((size_t)NLAYERS * 512 * 1024 * 2);
    float*  pooled= (float*) alloc((size_t)BATCH * DM * 4);
    float*  hid   = (float*) alloc((size_t)BATCH * 256 * 4);

    // ---- weight transposes (fp32 -> bf16, N x K layout) ----
    transpose_bf16_k<<<dim3(64, 16, 8), 256, 0, stream>>>(
        Win, WinT, 512, 2048, (long)512 * 2048, (long)2048 * 512);
    transpose_bf16_k<<<dim3(4, 32, 8), 256, 0, stream>>>(
        Wx, WxT, 1024, 64, (long)1024 * 64, (long)128 * 1024);      // pad N->128
    transpose_bf16_k<<<dim3(32, 1, 8), 256, 0, stream>>>(
        Wdt, WdtT, 32, 1024, (long)32 * 1024, (long)1024 * 32);
    transpose_bf16_k<<<dim3(16, 32, 8), 256, 0, stream>>>(
        Wout, WoutT, 1024, 512, (long)1024 * 512, (long)512 * 1024);

    // ---- patch + pos embed ----
    patch_k<<<(ROWS * DM) / 256, 256, 0, stream>>>(x, patch_w, patch_b, pos, h);

    for (int layer = 0; layer < NLAYERS; ++layer) {
        layernorm_bf16_k<<<(ROWS + 3) / 4, 256, 0, stream>>>(
            h, ln_g + layer * DM, ln_b + layer * DM, hln, ROWS);
        // xz = hln @ Win   (M=6272, N=2048, K=512)
        gemm_bf16<<<dim3(16, 49), 256, 0, stream>>>(
            hln, 512, WinT + (size_t)layer * 2048 * 512, 512, nullptr,
            xz, 2048, ROWS, 2048, 512, 0, 0, nullptr);
        conv_silu_k<<<(ROWS * DINNER) / 256, 256, 0, stream>>>(
            xz, conv_w + (size_t)layer * DINNER * DCONV,
            conv_b + (size_t)layer * DINNER, xp, xpb);
        // dbc = xp @ Wx    (M=6272, N=64, K=1024)
        gemm_bf16<<<dim3(1, 49), 256, 0, stream>>>(
            xpb, 1024, WxT + (size_t)layer * 128 * 1024, 1024, nullptr,
            dbc, 64, ROWS, 64, 1024, 0, 0, nullptr);
        dtlo_k<<<(ROWS * 32) / 256, 256, 0, stream>>>(dbc, dtlo);
        // dt = softplus(dt_lo @ Wdt + bdt)  (M=6272, N=1024, K=32) -> bf16
        gemm_bf16<<<dim3(8, 49), 256, 0, stream>>>(
            dtlo, 32, WdtT + (size_t)layer * 1024 * 32, 32,
            bdt + (size_t)layer * DINNER,
            nullptr, 1024, ROWS, 1024, 32, 1, 0, dtb);
        // selective scan (+ D skip + silu(z) gate) -> y (bf16, reuses xpb)
        scan_k<<<BATCH * 4, 256, 0, stream>>>(
            xp, dtb, dbc, xz,
            A_log + (size_t)layer * DINNER * DSTATE,
            Dp + (size_t)layer * DINNER, xpb);
        // h += y @ Wout    (M=6272, N=512, K=1024)
        gemm_bf16<<<dim3(4, 49), 256, 0, stream>>>(
            xpb, 1024, WoutT + (size_t)layer * 512 * 1024, 1024, nullptr,
            h, 512, ROWS, 512, 1024, 0, 1, nullptr);
    }

    pool_ln_k<<<BATCH, 256, 0, stream>>>(h, norm_g, norm_b, pooled);
    gemm_f32<<<dim3(4, 2), 256, 0, stream>>>(
        pooled, DM, W1, 256, hid, 256, BATCH, 256, DM, b1, 2);
    gemm_f32<<<dim3(1, 2), 256, 0, stream>>>(
        hid, 256, W2, 10, out, 10, BATCH, 10, 256, b2, 0);
}

// Round 3
// 1768.309 us; speedup vs baseline: 4.1317x; 1.2537x over previous
//
#include <hip/hip_runtime.h>
#include <math.h>

// ---- model dims ----
#define BATCH   128
#define LSEQ    49
#define DM      512
#define NLAYERS 8
#define DSTATE  16
#define DCONV   4
#define DINNER  1024
#define DTRANK  32
#define EPSV    1e-5f
#define ROWS (BATCH*LSEQ)   // 6272

typedef unsigned short bf16_t;
typedef __attribute__((ext_vector_type(8))) short short8;   // 8 bf16 (4 VGPRs)
typedef __attribute__((ext_vector_type(4))) float f32x4;

__device__ __forceinline__ bf16_t f2b(float f) {
    union { float f; unsigned u; } v; v.f = f;
    return (bf16_t)((v.u + 0x7fffu + ((v.u >> 16) & 1u)) >> 16);   // RNE
}
__device__ __forceinline__ void gload_lds16(const void* g, void* l) {
    __builtin_amdgcn_global_load_lds(
        (const __attribute__((address_space(1))) unsigned int*)g,
        (__attribute__((address_space(3))) unsigned int*)l, 16, 0, 0);
}

// =====================================================================
// bf16 MFMA GEMM, m97 structure: 128x128 tile, BK=32, global_load_lds x16B.
// A: M x K row-major bf16.  Bt: N x K row-major bf16 (B transposed).
// Optional split-K: ksz>0 -> block z handles K-chunk [z*ksz, z*ksz+ksz),
// writing to C + z*cstride (partial outputs, summed by the consumer).
// Requires M%128==0, K%32==0; N-edge via store guard (Bt padded to 128 rows).
// =====================================================================
__global__ __launch_bounds__(256) void gemm_bf16(
    const bf16_t* __restrict__ A, int lda,
    const bf16_t* __restrict__ Bt, int ldb,
    float* __restrict__ C, int ldc,
    int M, int N, int K, int accum,
    int ksz, long cstride)
{
    __shared__ bf16_t As[128 * 32];   // row-major, 64B per row
    __shared__ bf16_t Bs[128 * 32];

    const int tid  = threadIdx.x;
    const int wave = tid >> 6;
    const int lane = tid & 63;
    const int bm = blockIdx.y * 128;
    const int bn = blockIdx.x * 128;
    const int wr = wave >> 1;
    const int wc = wave & 1;
    const int q  = lane >> 4;
    const int lm = lane & 15;

    int kbeg = 0, kend = K;
    if (ksz > 0) {
        kbeg = blockIdx.z * ksz;
        kend = kbeg + ksz;
        C += (size_t)blockIdx.z * cstride;
    }

    const int rowInChunk = lane >> 2;        // 0..15
    const int col8 = (lane & 3) * 8;

    f32x4 acc[4][4];
    #pragma unroll
    for (int i = 0; i < 4; ++i)
        #pragma unroll
        for (int j = 0; j < 4; ++j)
            acc[i][j] = (f32x4){0.f, 0.f, 0.f, 0.f};

    for (int k0 = kbeg; k0 < kend; k0 += 32) {
        #pragma unroll
        for (int i = 0; i < 2; ++i) {
            int chunk = wave * 2 + i;
            int r = chunk * 16 + rowInChunk;
            const bf16_t* ga = A  + (size_t)(bm + r) * lda + k0 + col8;
            const bf16_t* gb = Bt + (size_t)(bn + r) * ldb + k0 + col8;
            gload_lds16(ga, &As[chunk * 512]);
            gload_lds16(gb, &Bs[chunk * 512]);
        }
        __syncthreads();

        short8 af[4], bq[4];
        #pragma unroll
        for (int t = 0; t < 4; ++t) {
            af[t] = *(const short8*)&As[(wr * 64 + t * 16 + lm) * 32 + q * 8];
            bq[t] = *(const short8*)&Bs[(wc * 64 + t * 16 + lm) * 32 + q * 8];
        }
        #pragma unroll
        for (int mt = 0; mt < 4; ++mt)
            #pragma unroll
            for (int nt = 0; nt < 4; ++nt)
                acc[mt][nt] = __builtin_amdgcn_mfma_f32_16x16x32_bf16(
                    af[mt], bq[nt], acc[mt][nt], 0, 0, 0);
        __syncthreads();
    }

    // epilogue: C/D layout col=lane&15, row=q*4+reg
    #pragma unroll
    for (int mt = 0; mt < 4; ++mt) {
        #pragma unroll
        for (int nt = 0; nt < 4; ++nt) {
            int col = bn + wc * 64 + nt * 16 + lm;
            if (col >= N) continue;
            #pragma unroll
            for (int r = 0; r < 4; ++r) {
                int row = bm + wr * 64 + mt * 16 + q * 4 + r;
                float c = acc[mt][nt][r];
                size_t idx = (size_t)row * ldc + col;
                if (accum) c += C[idx];
                C[idx] = c;
            }
        }
    }
}

// ---- transpose + fp32->bf16 convert: out[z][n][k] = in[z][k][n], pad n>=Nd=0
__global__ __launch_bounds__(256) void transpose_bf16_k(
    const float* __restrict__ in, bf16_t* __restrict__ out,
    int Kd, int Nd, long in_stride, long out_stride)
{
    __shared__ float tile[32][33];
    int z = blockIdx.z;
    const float* src = in + (size_t)z * in_stride;
    bf16_t* dst = out + (size_t)z * out_stride;
    int n0 = blockIdx.x * 32, k0 = blockIdx.y * 32;
    int tx = threadIdx.x & 31, ty = threadIdx.x >> 5;  // ty 0..7
    #pragma unroll
    for (int i = 0; i < 4; ++i) {
        int n = n0 + tx;
        tile[ty + i * 8][tx] = (n < Nd) ? src[(size_t)(k0 + ty + i * 8) * Nd + n] : 0.f;
    }
    __syncthreads();
    #pragma unroll
    for (int i = 0; i < 4; ++i) {
        int n = n0 + ty + i * 8;
        dst[(size_t)n * Kd + k0 + tx] = f2b(tile[tx][ty + i * 8]);
    }
}

// ---- patch embed + pos embed ----
__global__ __launch_bounds__(256) void patch_k(
    const float* __restrict__ x, const float* __restrict__ pw,
    const float* __restrict__ pb, const float* __restrict__ pos,
    float* __restrict__ h)
{
    int idx = blockIdx.x * 256 + threadIdx.x;
    int d = idx & (DM - 1);
    int l = (idx >> 9) % LSEQ;
    int b = idx / (DM * LSEQ);
    int gi = l / 7, gj = l % 7;
    float acc = pb[d];
    #pragma unroll
    for (int k = 0; k < 16; ++k) {
        int pi = k >> 2, pj = k & 3;
        acc = fmaf(x[((long)b * 28 + gi * 4 + pi) * 28 + gj * 4 + pj],
                   pw[d * 16 + k], acc);
    }
    h[idx] = acc + pos[l * DM + d];
}

// ---- layernorm (512) -> bf16, one wave per row ----
__global__ __launch_bounds__(256) void layernorm_bf16_k(
    const float* __restrict__ x, const float* __restrict__ g,
    const float* __restrict__ bb, bf16_t* __restrict__ y, int rows)
{
    int wave = threadIdx.x >> 6;
    int lane = threadIdx.x & 63;
    int row = blockIdx.x * 4 + wave;
    if (row >= rows) return;
    const float* xr = x + (long)row * DM;
    float v[8];
    float s = 0.f, qq = 0.f;
    #pragma unroll
    for (int i = 0; i < 8; ++i) {
        v[i] = xr[lane * 8 + i];
        s += v[i]; qq += v[i] * v[i];
    }
    #pragma unroll
    for (int o = 32; o > 0; o >>= 1) {
        s += __shfl_down(s, o, 64);
        qq += __shfl_down(qq, o, 64);
    }
    s = __shfl(s, 0, 64); qq = __shfl(qq, 0, 64);
    float m = s * (1.f / DM);
    float var = qq * (1.f / DM) - m * m;
    float rs = rsqrtf(var + EPSV);
    bf16_t* yr = y + (long)row * DM;
    #pragma unroll
    for (int i = 0; i < 8; ++i) {
        int c = lane * 8 + i;
        yr[c] = f2b((v[i] - m) * rs * g[c] + bb[c]);
    }
}

// ---- causal depthwise conv (k=4) + silu; fp32 + bf16 outputs ----
__global__ __launch_bounds__(256) void conv_silu_k(
    const float* __restrict__ xz, const float* __restrict__ cw,
    const float* __restrict__ cb, float* __restrict__ xp,
    bf16_t* __restrict__ xpb)
{
    int idx = blockIdx.x * 256 + threadIdx.x;
    int d = idx & (DINNER - 1);
    int l = (idx >> 10) % LSEQ;
    int b = idx / (DINNER * LSEQ);
    float acc = cb[d];
    #pragma unroll
    for (int k = 0; k < DCONV; ++k) {
        int ls = l - 3 + k;
        if (ls >= 0)
            acc = fmaf(xz[(long)(b * LSEQ + ls) * (2 * DINNER) + d],
                       cw[d * DCONV + k], acc);
    }
    acc = acc / (1.f + __expf(-acc));
    xp[idx] = acc;
    xpb[idx] = f2b(acc);
}

// =====================================================================
// Fused: sum split-K dbc partials + dt GEMM (K=32) + softplus + selective
// scan + D-skip + silu(z) gate. One block per (batch, d-quarter).
// =====================================================================
__global__ __launch_bounds__(256) void scan2_k(
    const float* __restrict__ xp,     // (ROWS, DINNER) fp32
    const float* __restrict__ dbcp,   // 4 partials of (ROWS, 64), stride PS
    const float* __restrict__ xz,     // (ROWS, 2048), z at 1024+
    const float* __restrict__ Wdt,    // layer base: (32, 1024) row-major
    const float* __restrict__ bdt,    // layer base: (1024)
    const float* __restrict__ A_log,  // layer base: (1024, 16)
    const float* __restrict__ Dp,     // layer base: (1024)
    bf16_t* __restrict__ y)           // (ROWS, DINNER) bf16
{
    __shared__ float sW[32][256];     // Wdt slice (k, d-in-block)
    __shared__ float sdt[LSEQ][32];   // dt_lo rows for this batch
    __shared__ float smB[LSEQ][DSTATE];
    __shared__ float smC[LSEQ][DSTATE];

    const int t = threadIdx.x;
    const int b = blockIdx.x >> 2;
    const int quarter = blockIdx.x & 3;
    const int d = quarter * 256 + t;
    const long PS = (long)ROWS * 64;

    #pragma unroll
    for (int k = 0; k < 32; ++k)
        sW[k][t] = Wdt[k * 1024 + d];

    for (int e = t; e < LSEQ * 32; e += 256) {
        int l = e >> 5, k = e & 31;
        long base = (long)(b * LSEQ + l) * 64 + k;
        sdt[l][k] = dbcp[base] + dbcp[base + PS] + dbcp[base + 2 * PS] + dbcp[base + 3 * PS];
    }
    for (int e = t; e < LSEQ * DSTATE; e += 256) {
        int l = e >> 4, n = e & 15;
        long base = (long)(b * LSEQ + l) * 64;
        smB[l][n] = dbcp[base + 32 + n] + dbcp[base + 32 + n + PS]
                  + dbcp[base + 32 + n + 2 * PS] + dbcp[base + 32 + n + 3 * PS];
        smC[l][n] = dbcp[base + 48 + n] + dbcp[base + 48 + n + PS]
                  + dbcp[base + 48 + n + 2 * PS] + dbcp[base + 48 + n + 3 * PS];
    }
    __syncthreads();

    float Arow[DSTATE];
    #pragma unroll
    for (int n = 0; n < DSTATE; ++n)
        Arow[n] = -expf(A_log[d * DSTATE + n]);   // exact exp (fixes r1 bug)
    const float Dv = Dp[d];
    const float bdtv = bdt[d];

    float h[DSTATE] = {};
    for (int l = 0; l < LSEQ; ++l) {
        const long r = (long)(b * LSEQ + l);
        // dt = softplus(dt_lo @ Wdt + bdt)
        float dtv = bdtv;
        #pragma unroll 8
        for (int k = 0; k < 32; ++k)
            dtv = fmaf(sdt[l][k], sW[k][t], dtv);
        dtv = (dtv > 20.f) ? dtv : log1pf(__expf(dtv));

        const float xv = xp[r * DINNER + d];
        float acc = 0.f;
        #pragma unroll
        for (int n = 0; n < DSTATE; ++n) {
            float dA = __expf(dtv * Arow[n]);
            h[n] = dA * h[n] + dtv * smB[l][n] * xv;
            acc = fmaf(h[n], smC[l][n], acc);
        }
        acc = fmaf(Dv, xv, acc);
        const float zv = xz[r * (2 * DINNER) + DINNER + d];
        acc *= zv / (1.f + __expf(-zv));
        y[r * DINNER + d] = f2b(acc);
    }
}

// =====================================================================
// Fused head: mean over L + layernorm + W1 + gelu + W2. One block / batch.
// =====================================================================
__global__ __launch_bounds__(256) void head_k(
    const float* __restrict__ h, const float* __restrict__ g,
    const float* __restrict__ bb,
    const float* __restrict__ W1, const float* __restrict__ b1,
    const float* __restrict__ W2, const float* __restrict__ b2,
    float* __restrict__ out)
{
    __shared__ float pl[DM];
    __shared__ float hd[256];
    __shared__ float red[8];
    const int b = blockIdx.x;
    const int t = threadIdx.x;
    const int c0 = t, c1 = t + 256;
    float v0 = 0.f, v1 = 0.f;
    for (int l = 0; l < LSEQ; ++l) {
        const float* row = h + (long)(b * LSEQ + l) * DM;
        v0 += row[c0]; v1 += row[c1];
    }
    v0 *= (1.f / LSEQ); v1 *= (1.f / LSEQ);
    float s = v0 + v1, q = v0 * v0 + v1 * v1;
    #pragma unroll
    for (int o = 32; o > 0; o >>= 1) {
        s += __shfl_down(s, o, 64);
        q += __shfl_down(q, o, 64);
    }
    int lane = t & 63, wave = t >> 6;
    if (lane == 0) { red[wave] = s; red[4 + wave] = q; }
    __syncthreads();
    if (t == 0) {
        float S = red[0] + red[1] + red[2] + red[3];
        float Q = red[4] + red[5] + red[6] + red[7];
        float m = S * (1.f / DM);
        red[0] = m;
        red[1] = rsqrtf(Q * (1.f / DM) - m * m + EPSV);
    }
    __syncthreads();
    float m = red[0], rs = red[1];
    pl[c0] = (v0 - m) * rs * g[c0] + bb[c0];
    pl[c1] = (v1 - m) * rs * g[c1] + bb[c1];
    __syncthreads();

    // hid = gelu(pooled @ W1 + b1): thread t -> column t
    float a = b1[t];
    #pragma unroll 16
    for (int k = 0; k < DM; ++k)
        a = fmaf(pl[k], W1[k * 256 + t], a);
    a = 0.5f * a * (1.f + erff(a * 0.7071067811865476f));
    hd[t] = a;
    __syncthreads();

    // out = hid @ W2 + b2
    if (t < 10) {
        float o = b2[t];
        #pragma unroll 16
        for (int k = 0; k < 256; ++k)
            o = fmaf(hd[k], W2[k * 10 + t], o);
        out[b * 10 + t] = o;
    }
}

extern "C" void kernel_launch(void* const* d_in, const int* in_sizes, int n_in,
                              void* d_out, int out_size, void* d_ws, size_t ws_size,
                              hipStream_t stream)
{
    const float* x       = (const float*)d_in[0];
    const float* patch_w = (const float*)d_in[1];
    const float* patch_b = (const float*)d_in[2];
    const float* pos     = (const float*)d_in[3];
    const float* Win     = (const float*)d_in[4];
    const float* conv_w  = (const float*)d_in[5];
    const float* conv_b  = (const float*)d_in[6];
    const float* Wx      = (const float*)d_in[7];
    const float* Wdt     = (const float*)d_in[8];
    const float* bdt     = (const float*)d_in[9];
    const float* A_log   = (const float*)d_in[10];
    const float* Dp      = (const float*)d_in[11];
    const float* Wout    = (const float*)d_in[12];
    const float* ln_g    = (const float*)d_in[13];
    const float* ln_b    = (const float*)d_in[14];
    const float* norm_g  = (const float*)d_in[15];
    const float* norm_b  = (const float*)d_in[16];
    const float* W1      = (const float*)d_in[17];
    const float* b1      = (const float*)d_in[18];
    const float* W2      = (const float*)d_in[19];
    const float* b2      = (const float*)d_in[20];
    float* out = (float*)d_out;

    // ---- workspace carve (aligned 256B) ----
    char* p = (char*)d_ws;
    auto alloc = [&](size_t bytes) {
        char* r = p; p += (bytes + 255) & ~(size_t)255; return r;
    };
    float*  h     = (float*) alloc((size_t)ROWS * DM * 4);
    float*  xz    = (float*) alloc((size_t)ROWS * 2 * DINNER * 4);
    float*  xp    = (float*) alloc((size_t)ROWS * DINNER * 4);
    float*  dbcp  = (float*) alloc((size_t)4 * ROWS * 64 * 4);   // 4 split-K partials
    bf16_t* hln   = (bf16_t*)alloc((size_t)ROWS * DM * 2);
    bf16_t* xpb   = (bf16_t*)alloc((size_t)ROWS * DINNER * 2);  // also y
    bf16_t* WinT  = (bf16_t*)alloc((size_t)NLAYERS * 2048 * 512 * 2);
    bf16_t* WxT   = (bf16_t*)alloc((size_t)NLAYERS * 128 * 1024 * 2);
    bf16_t* WoutT = (bf16_t*)alloc((size_t)NLAYERS * 512 * 1024 * 2);

    // ---- weight transposes (fp32 -> bf16, N x K layout) ----
    transpose_bf16_k<<<dim3(64, 16, 8), 256, 0, stream>>>(
        Win, WinT, 512, 2048, (long)512 * 2048, (long)2048 * 512);
    transpose_bf16_k<<<dim3(4, 32, 8), 256, 0, stream>>>(
        Wx, WxT, 1024, 64, (long)1024 * 64, (long)128 * 1024);      // pad N->128
    transpose_bf16_k<<<dim3(16, 32, 8), 256, 0, stream>>>(
        Wout, WoutT, 1024, 512, (long)1024 * 512, (long)512 * 1024);

    // ---- patch + pos embed ----
    patch_k<<<(ROWS * DM) / 256, 256, 0, stream>>>(x, patch_w, patch_b, pos, h);

    for (int layer = 0; layer < NLAYERS; ++layer) {
        layernorm_bf16_k<<<(ROWS + 3) / 4, 256, 0, stream>>>(
            h, ln_g + layer * DM, ln_b + layer * DM, hln, ROWS);
        // xz = hln @ Win   (M=6272, N=2048, K=512)
        gemm_bf16<<<dim3(16, 49), 256, 0, stream>>>(
            hln, 512, WinT + (size_t)layer * 2048 * 512,
            512, xz, 2048, ROWS, 2048, 512, 0, 0, 0);
        conv_silu_k<<<(ROWS * DINNER) / 256, 256, 0, stream>>>(
            xz, conv_w + (size_t)layer * DINNER * DCONV,
            conv_b + (size_t)layer * DINNER, xp, xpb);
        // dbc partials = xp @ Wx  (M=6272, N=64, K=1024, split-K x4)
        gemm_bf16<<<dim3(1, 49, 4), 256, 0, stream>>>(
            xpb, 1024, WxT + (size_t)layer * 128 * 1024,
            1024, dbcp, 64, ROWS, 64, 1024, 0, 256, (long)ROWS * 64);
        // fused dt-GEMM + softplus + selective scan + gate -> y (reuses xpb)
        scan2_k<<<BATCH * 4, 256, 0, stream>>>(
            xp, dbcp, xz,
            Wdt + (size_t)layer * DTRANK * DINNER,
            bdt + (size_t)layer * DINNER,
            A_log + (size_t)layer * DINNER * DSTATE,
            Dp + (size_t)layer * DINNER, xpb);
        // h += y @ Wout    (M=6272, N=512, K=1024)
        gemm_bf16<<<dim3(4, 49), 256, 0, stream>>>(
            xpb, 1024, WoutT + (size_t)layer * 512 * 1024,
            1024, h, 512, ROWS, 512, 1024, 1, 0, 0);
    }

    // ---- fused head: pool + LN + W1 + gelu + W2 ----
    head_k<<<BATCH, 256, 0, stream>>>(h, norm_g, norm_b, W1, b1, W2, b2, out);
}